// Round 4
// baseline (351.038 us; speedup 1.0000x reference)
//
#include <hip/hip_runtime.h>
#include <hip/hip_bf16.h>
#include <stdint.h>

// ============================================================================
// AdaptiveEdgeDropping: out = matrix with top-k (k = E*pct/100) of
// (log_sigmoid(dp*(1-v) - g*v) + gumbel(key=42)) zeroed.  BIT-EXACT.
//
// Round 4: one-level 8192-bin radix bracket on APPROX keys (HW transcendental,
// |approx-exact| <= ~5e-7 << DELTA=1e-3), streaming output pass with
// LDS-compacted band-index list (NO exact eval in hot loop -> no divergence
// stall), dense exact eval over the ~200K-element band, exact 16+16-bit
// select with stable ties (lowest index first).
// ============================================================================

#define NBINS 8192
#define NBINS_SHIFT 19            // code>>19 -> 13-bit bin
#define NB 512                    // histogram blocks
#define LIST_CAP 2097152u
#define MINI_CAP 4096u
#define DELTA 1e-3f
#define LBUF_CAP 2048

// ---------------- threefry2x32, key=(0,42), counts=(0,i), out = x0^x1 -------
__device__ __forceinline__ unsigned tf_bits(unsigned i) {
  const unsigned ks0 = 0u;
  const unsigned ks1 = 42u;
  const unsigned ks2 = 0x1BD11BDAu ^ 0u ^ 42u;
  unsigned x0 = 0u + ks0;
  unsigned x1 = i + ks1;
#define TF_R(rot) { x0 += x1; x1 = (x1 << (rot)) | (x1 >> (32 - (rot))); x1 ^= x0; }
  TF_R(13) TF_R(15) TF_R(26) TF_R(6)
  x0 += ks1; x1 += ks2 + 1u;
  TF_R(17) TF_R(29) TF_R(16) TF_R(24)
  x0 += ks2; x1 += ks0 + 2u;
  TF_R(13) TF_R(15) TF_R(26) TF_R(6)
  x0 += ks0; x1 += ks1 + 3u;
  TF_R(17) TF_R(29) TF_R(16) TF_R(24)
  x0 += ks1; x1 += ks2 + 4u;
  TF_R(13) TF_R(15) TF_R(26) TF_R(6)
  x0 += ks2; x1 += ks0 + 5u;
#undef TF_R
  return x0 ^ x1;
}

// ---------------- jax.random.uniform(minval=1e-7, maxval=1-1e-7) -----------
__device__ __forceinline__ float uniform_from_bits(unsigned bits) {
  unsigned fb = (bits >> 9) | 0x3f800000u;
  float f = __uint_as_float(fb) - 1.0f;
  const float minv = 1e-7f;
  const float maxv = __uint_as_float(0x3F7FFFFEu);   // f32(1.0 - 1e-7)
  float r = __fsub_rn(maxv, minv);
  float u = __fadd_rn(__fmul_rn(f, r), minv);
  return fmaxf(minv, u);
}

// ---------------- XLA-CPU Cephes expf (unfused) ----------------------------
__device__ __forceinline__ float xla_expf(float input) {
  const float exp_hi = 88.3762626647950f;
  const float exp_lo = -88.3762626647949f;
  float x = fminf(fmaxf(input, exp_lo), exp_hi);
  float fx = floorf(__fadd_rn(__fmul_rn(x, 1.44269504088896341f), 0.5f));
  float tmp = __fmul_rn(0.693359375f, fx);
  float z = __fmul_rn(-2.12194440e-4f, fx);
  x = __fsub_rn(x, tmp);
  x = __fsub_rn(x, z);
  z = __fmul_rn(x, x);
  float y = __fadd_rn(__fmul_rn(x, 1.9875691500e-4f), 1.3981999507e-3f);
  y = __fadd_rn(__fmul_rn(y, x), 8.3334519073e-3f);
  y = __fadd_rn(__fmul_rn(y, x), 4.1665795894e-2f);
  y = __fadd_rn(__fmul_rn(y, x), 1.6666665459e-1f);
  y = __fadd_rn(__fmul_rn(y, x), 5.0000001201e-1f);
  y = __fadd_rn(__fmul_rn(y, z), x);
  y = __fadd_rn(1.0f, y);
  int n = (int)fx;
  float p2n = __int_as_float((n + 0x7f) << 23);
  return fmaxf(__fmul_rn(y, p2n), input);
}

// ---------------- XLA-CPU Cephes logf (Estrin, unfused) --------------------
__device__ __forceinline__ float xla_logf(float input) {
  float t0 = fmaxf(input, __uint_as_float(0x00800000u));
  unsigned ib = __float_as_uint(t0);
  int emm0 = (int)(ib >> 23) - 0x7f;
  float e = __fadd_rn(1.0f, (float)emm0);
  float m = __uint_as_float((ib & 0x807fffffu) | 0x3f000000u);
  bool mask = m < 0.707106781186547524f;
  float t1 = mask ? m : 0.0f;
  m = __fsub_rn(m, 1.0f);
  e = __fsub_rn(e, mask ? 1.0f : 0.0f);
  m = __fadd_rn(m, t1);
  float x2 = __fmul_rn(m, m);
  float x3 = __fmul_rn(x2, m);
  float y  = __fadd_rn(__fmul_rn(m, 7.0376836292e-2f), -1.1514610310e-1f);
  float y1 = __fadd_rn(__fmul_rn(m, -1.2420140846e-1f), 1.4249322787e-1f);
  float y2 = __fadd_rn(__fmul_rn(m, 2.0000714765e-1f), -2.4999993993e-1f);
  y  = __fadd_rn(__fmul_rn(y, m), 1.1676998740e-1f);
  y1 = __fadd_rn(__fmul_rn(y1, m), -1.6668057665e-1f);
  y2 = __fadd_rn(__fmul_rn(y2, m), 3.3333331174e-1f);
  y = __fadd_rn(__fmul_rn(y, x3), y1);
  y = __fadd_rn(__fmul_rn(y, x3), y2);
  y = __fmul_rn(y, x3);
  y = __fadd_rn(y, __fmul_rn(-2.12194440e-4f, e));
  y = __fsub_rn(y, __fmul_rn(0.5f, x2));
  m = __fadd_rn(m, y);
  m = __fadd_rn(m, __fmul_rn(0.693359375f, e));
  return m;
}

// ---------------- XLA elemental log1p --------------------------------------
__device__ __forceinline__ float xla_log1pf(float x) {
  float for_large = xla_logf(__fadd_rn(x, 1.0f));
  float for_small = __fmul_rn(__fadd_rn(__fmul_rn(-0.5f, x), 1.0f), x);
  return (fabsf(x) < 1e-4f) ? for_small : for_large;
}

// ---------------- monotone code <-> float ----------------------------------
__device__ __forceinline__ unsigned encode_f(float f) {
  unsigned b = __float_as_uint(f);
  return (b & 0x80000000u) ? ~b : (b | 0x80000000u);
}
__device__ __forceinline__ float decode_f(unsigned c) {
  unsigned b = (c & 0x80000000u) ? (c ^ 0x80000000u) : ~c;
  return __uint_as_float(b);
}

// ---------------- EXACT per-element key code (verified bit-exact) ----------
__device__ __forceinline__ unsigned compute_ou(unsigned i, float v, float dp, float g) {
  if (v == 0.0f) return 0u;
  unsigned bits = tf_bits(i);
  float u = uniform_from_bits(bits);
  float lg = xla_logf(u);
  float gum = -xla_logf(-lg);
  float t = __fsub_rn(1.0f, v);
  float lx = __fsub_rn(__fmul_rn(dp, t), __fmul_rn(g, v));
  float ex = xla_expf(-fabsf(lx));
  float l1p = xla_log1pf(ex);
  float lp = -(__fadd_rn(fmaxf(-lx, 0.0f), l1p));
  float key = __fadd_rn(lp, gum);
  return encode_f(key);
}

// ---------------- APPROX key code (HW transcendentals, |err| <= ~5e-7) -----
__device__ __forceinline__ unsigned approx_code(unsigned i, float v, float dp, float g) {
  if (v == 0.0f) return 0u;
  unsigned bits = tf_bits(i);
  float u = uniform_from_bits(bits);
  float lg = __logf(u);
  float gum = -__logf(-lg);
  float t = __fsub_rn(1.0f, v);
  float lx = __fsub_rn(__fmul_rn(dp, t), __fmul_rn(g, v));
  float ex = __expf(-fabsf(lx));
  float for_small = __fmul_rn(__fadd_rn(__fmul_rn(-0.5f, ex), 1.0f), ex);
  float l1p = (fabsf(ex) < 1e-4f) ? for_small : __logf(__fadd_rn(ex, 1.0f));
  float lp = -(__fadd_rn(fmaxf(-lx, 0.0f), l1p));
  float key = __fadd_rn(lp, gum);
  return encode_f(key);
}

// ============================================================================
// K1: keys (approx if stored, exact fallback), LDS 8192-bin hist, row flush.
// ============================================================================
__global__ __launch_bounds__(512) void key_hist1_kernel(
    const float* __restrict__ v, const float* __restrict__ dpp,
    const float* __restrict__ gp, unsigned* __restrict__ keys,
    unsigned* __restrict__ blockhist, int E) {
  __shared__ unsigned h[NBINS];
  for (int j = threadIdx.x; j < NBINS; j += 512) h[j] = 0;
  __syncthreads();
  float dp = dpp[0], g = gp[0];
  int nvec = E >> 2;
  int stride = gridDim.x * 512;
  for (int iv = blockIdx.x * 512 + threadIdx.x; iv < nvec; iv += stride) {
    float4 vv = reinterpret_cast<const float4*>(v)[iv];
    unsigned base = (unsigned)iv << 2;
    unsigned o0, o1, o2, o3;
    if (keys) {
      o0 = approx_code(base + 0u, vv.x, dp, g);
      o1 = approx_code(base + 1u, vv.y, dp, g);
      o2 = approx_code(base + 2u, vv.z, dp, g);
      o3 = approx_code(base + 3u, vv.w, dp, g);
      reinterpret_cast<uint4*>(keys)[iv] = make_uint4(o0, o1, o2, o3);
    } else {
      o0 = compute_ou(base + 0u, vv.x, dp, g);
      o1 = compute_ou(base + 1u, vv.y, dp, g);
      o2 = compute_ou(base + 2u, vv.z, dp, g);
      o3 = compute_ou(base + 3u, vv.w, dp, g);
    }
    atomicAdd(&h[o0 >> NBINS_SHIFT], 1u);
    atomicAdd(&h[o1 >> NBINS_SHIFT], 1u);
    atomicAdd(&h[o2 >> NBINS_SHIFT], 1u);
    atomicAdd(&h[o3 >> NBINS_SHIFT], 1u);
  }
  if (blockIdx.x == 0) {                       // tail (E % 4)
    for (int i = (nvec << 2) + threadIdx.x; i < E; i += 512) {
      float val = v[i];
      unsigned ou = keys ? approx_code((unsigned)i, val, dp, g)
                         : compute_ou((unsigned)i, val, dp, g);
      if (keys) keys[i] = ou;
      atomicAdd(&h[ou >> NBINS_SHIFT], 1u);
    }
  }
  __syncthreads();
  unsigned* row = blockhist + (size_t)blockIdx.x * NBINS;
  for (int j = threadIdx.x; j < NBINS; j += 512) row[j] = h[j];
}

// ============================================================================
// K2: hist[j] += sum_b blockhist[b][j]   (hist pre-zeroed; 8 slices)
// ============================================================================
#define RED_SLICES 8
__global__ __launch_bounds__(256) void reduce_hist_kernel(
    const unsigned* __restrict__ blockhist, unsigned* __restrict__ hist) {
  int gid = blockIdx.x * 256 + threadIdx.x;   // 256 blocks -> 65536 threads
  int j = gid & (NBINS - 1);
  int slice = gid >> 13;                      // 0..7
  unsigned s = 0;
  for (int b = slice; b < NB; b += RED_SLICES)
    s += blockhist[(size_t)b * NBINS + j];
  atomicAdd(&hist[j], s);
}

// ============================================================================
// K3: single-level select over 8192 bins -> band [blo, bhi] with +-delta.
// state[0]=B, state[2]=blo, state[3]=bhi, state[6]=k.
// ============================================================================
__global__ __launch_bounds__(1024) void find_sel_kernel(
    const unsigned* __restrict__ hist, unsigned* __restrict__ state,
    const int* __restrict__ pct_p, long long Etot, float delta) {
  __shared__ unsigned s[1024];
  int t = threadIdx.x;
  unsigned hh[8];
  unsigned tot = 0;
  #pragma unroll
  for (int j = 0; j < 8; ++j) { hh[j] = hist[t * 8 + j]; tot += hh[j]; }
  s[t] = tot;
  __syncthreads();
  for (int off = 1; off < 1024; off <<= 1) {
    unsigned add = (t + off < 1024) ? s[t + off] : 0u;
    __syncthreads();
    s[t] += add;
    __syncthreads();
  }
  long long k = (Etot * (long long)pct_p[0]) / 100;
  long long above_next = (t < 1023) ? (long long)s[t + 1] : 0;
  if (above_next < k && k <= above_next + (long long)tot) {
    long long above = above_next;
    int b = 7;
    for (; b >= 0; --b) {
      if (above < k && k <= above + (long long)hh[b]) break;
      above += (long long)hh[b];
    }
    unsigned B = (unsigned)(t * 8 + b);
    state[0] = B;
    state[6] = (unsigned)k;
    float L = decode_f(B << NBINS_SHIFT);
    state[2] = encode_f(L - delta);
    if (B == NBINS - 1u) {
      state[3] = 0xFFFFFFFFu;
    } else {
      float H = decode_f((B + 1u) << NBINS_SHIFT);
      state[3] = encode_f(H + delta);
    }
  }
}

// ============================================================================
// K4: streaming output (code > bhi -> 0); band indices -> LDS-compacted list;
// |A| (outright drops) counted via shfl + one global atomic per block.
// NO exact evaluation here (avoids the R3 divergence stall).
// ============================================================================
__global__ __launch_bounds__(512) void output_kernel(
    const float* __restrict__ v, const float* __restrict__ dpp,
    const float* __restrict__ gp, const unsigned* __restrict__ keys,
    float* __restrict__ out, unsigned* __restrict__ state,
    unsigned* __restrict__ list, int E) {
  __shared__ unsigned lcnt, lbase, sacc;
  __shared__ unsigned lbuf[LBUF_CAP];
  if (threadIdx.x == 0) { lcnt = 0; sacc = 0; }
  __syncthreads();
  unsigned blo = state[2], bhi = state[3];
  float dp = dpp[0], g = gp[0];
  int nvec = E >> 2;
  int stride = gridDim.x * 512;
  unsigned acnt = 0;
  for (int iv = blockIdx.x * 512 + threadIdx.x; iv < nvec; iv += stride) {
    float4 vv = reinterpret_cast<const float4*>(v)[iv];
    unsigned base = (unsigned)iv << 2;
    unsigned os[4];
    if (keys) {
      uint4 kk = reinterpret_cast<const uint4*>(keys)[iv];
      os[0] = kk.x; os[1] = kk.y; os[2] = kk.z; os[3] = kk.w;
    } else {
      os[0] = compute_ou(base + 0u, vv.x, dp, g);
      os[1] = compute_ou(base + 1u, vv.y, dp, g);
      os[2] = compute_ou(base + 2u, vv.z, dp, g);
      os[3] = compute_ou(base + 3u, vv.w, dp, g);
    }
    float vals[4] = {vv.x, vv.y, vv.z, vv.w};
    float4 oo;
    float res[4];
    #pragma unroll
    for (int j = 0; j < 4; ++j) {
      bool drop = os[j] > bhi;
      acnt += drop ? 1u : 0u;
      res[j] = drop ? 0.0f : vals[j];
      if (!drop && os[j] >= blo) {
        unsigned p = atomicAdd(&lcnt, 1u);
        if (p < LBUF_CAP) lbuf[p] = base + (unsigned)j;
        else {
          unsigned q = atomicAdd(&state[4], 1u);
          if (q < LIST_CAP) list[q] = base + (unsigned)j;
        }
      }
    }
    oo.x = res[0]; oo.y = res[1]; oo.z = res[2]; oo.w = res[3];
    reinterpret_cast<float4*>(out)[iv] = oo;
  }
  if (blockIdx.x == 0) {
    for (int i = (nvec << 2) + threadIdx.x; i < E; i += 512) {
      float val = v[i];
      unsigned ou = keys ? keys[i] : compute_ou((unsigned)i, val, dp, g);
      bool drop = ou > bhi;
      acnt += drop ? 1u : 0u;
      out[i] = drop ? 0.0f : val;
      if (!drop && ou >= blo) {
        unsigned p = atomicAdd(&lcnt, 1u);
        if (p < LBUF_CAP) lbuf[p] = (unsigned)i;
        else {
          unsigned q = atomicAdd(&state[4], 1u);
          if (q < LIST_CAP) list[q] = (unsigned)i;
        }
      }
    }
  }
  // wave-reduce |A| then one LDS + one global atomic
  #pragma unroll
  for (int off = 32; off > 0; off >>= 1) acnt += __shfl_xor(acnt, off);
  if ((threadIdx.x & 63) == 0 && acnt) atomicAdd(&sacc, acnt);
  __syncthreads();
  if (threadIdx.x == 0) {
    unsigned n = min(lcnt, (unsigned)LBUF_CAP);
    lbase = atomicAdd(&state[4], n);
    if (sacc) atomicAdd(&state[5], sacc);
  }
  __syncthreads();
  unsigned n = min(lcnt, (unsigned)LBUF_CAP);
  for (unsigned j = threadIdx.x; j < n; j += 512) {
    unsigned q = lbase + j;
    if (q < LIST_CAP) list[q] = lbuf[j];
  }
}

// ============================================================================
// K5: dense exact eval over the band list; elist + 65536-bin ehist1.
// ============================================================================
__global__ __launch_bounds__(256) void exact_eval_kernel(
    const float* __restrict__ v, const float* __restrict__ dpp,
    const float* __restrict__ gp, const unsigned* __restrict__ list,
    unsigned* __restrict__ elist, const unsigned* __restrict__ state,
    unsigned* __restrict__ ehist1) {
  unsigned M = min(state[4], LIST_CAP);
  float dp = dpp[0], g = gp[0];
  for (unsigned e = blockIdx.x * 256 + threadIdx.x; e < M; e += gridDim.x * 256) {
    unsigned idx = list[e];
    unsigned ec = compute_ou(idx, v[idx], dp, g);
    elist[e] = ec;
    atomicAdd(&ehist1[ec >> 16], 1u);
  }
}

// ============================================================================
// K6/K8: 65536-bin suffix select. level 0: kp = k - |A| -> state[7]=E1,
// state[8]=r. level 1: kp = state[8] -> state[9]=Te code, state[10]=r2.
// ============================================================================
__global__ __launch_bounds__(1024) void find_e_kernel(
    const unsigned* __restrict__ eh, unsigned* __restrict__ state, int level) {
  __shared__ unsigned s[1024];
  int t = threadIdx.x;
  unsigned base = (unsigned)t * 64u;
  unsigned sum = 0;
  for (int j = 0; j < 64; ++j) sum += eh[base + j];
  s[t] = sum;
  __syncthreads();
  for (int off = 1; off < 1024; off <<= 1) {
    unsigned add = (t + off < 1024) ? s[t + off] : 0u;
    __syncthreads();
    s[t] += add;
    __syncthreads();
  }
  unsigned kp = (level == 0) ? (state[6] - state[5]) : state[8];
  if (kp == 0 || kp > s[0]) {
    if (t == 0) {
      if (level == 0) { state[7] = 0xFFFFFFFFu; state[8] = 0u; }
      else            { state[9] = 0xFFFFFFFFu; state[10] = 0u; }
    }
    return;
  }
  unsigned above_next = (t < 1023) ? s[t + 1] : 0u;
  if (above_next < kp && kp <= s[t]) {
    unsigned above = above_next;
    for (int b = 63; b >= 0; --b) {
      unsigned c = eh[base + (unsigned)b];
      if (above < kp && kp <= above + c) {
        unsigned bin = base + (unsigned)b;
        if (level == 0) { state[7] = bin; state[8] = kp - above; }
        else { state[9] = (state[7] << 16) | bin; state[10] = kp - above; }
        break;
      }
      above += c;
    }
  }
}

// ============================================================================
// K7: second-level exact hist (low 16 bits of members of bin E1).
// ============================================================================
__global__ __launch_bounds__(256) void scatter2_kernel(
    const unsigned* __restrict__ elist, const unsigned* __restrict__ state,
    unsigned* __restrict__ ehist2) {
  unsigned M = min(state[4], LIST_CAP);
  unsigned E1 = state[7];
  for (unsigned e = blockIdx.x * 256 + threadIdx.x; e < M; e += gridDim.x * 256) {
    unsigned ec = elist[e];
    if ((ec >> 16) == E1) atomicAdd(&ehist2[ec & 0xFFFFu], 1u);
  }
}

// ============================================================================
// K9: drop band members with ecode > Te; collect exact-tie indices.
// ============================================================================
__global__ __launch_bounds__(256) void band_drop_kernel(
    const unsigned* __restrict__ list, const unsigned* __restrict__ elist,
    unsigned* __restrict__ state, float* __restrict__ out,
    unsigned* __restrict__ mini) {
  unsigned M = min(state[4], LIST_CAP);
  unsigned Te = state[9];
  for (unsigned e = blockIdx.x * 256 + threadIdx.x; e < M; e += gridDim.x * 256) {
    unsigned ec = elist[e];
    if (ec > Te) out[list[e]] = 0.0f;
    else if (ec == Te) {
      unsigned q = atomicAdd(&state[11], 1u);
      if (q < MINI_CAP) mini[q] = list[e];
    }
  }
}

// ============================================================================
// K10: among exact-key ties, drop the r2 with the smallest indices.
// ============================================================================
__global__ __launch_bounds__(1024) void mini_ties_kernel(
    const unsigned* __restrict__ mini, const unsigned* __restrict__ state,
    float* __restrict__ out) {
  unsigned m = min(state[11], MINI_CAP);
  unsigned r2 = state[10];
  if (r2 == 0 || m == 0) return;
  for (unsigned e = threadIdx.x; e < m; e += 1024) {
    unsigned my = mini[e];
    unsigned rank = 0;
    for (unsigned j = 0; j < m; ++j) rank += (mini[j] < my) ? 1u : 0u;
    if (rank < r2) out[my] = 0.0f;
  }
}

// ---------------- launch ----------------------------------------------------
extern "C" void kernel_launch(void* const* d_in, const int* in_sizes, int n_in,
                              void* d_out, int out_size, void* d_ws, size_t ws_size,
                              hipStream_t stream) {
  const float* v  = (const float*)d_in[0];
  const float* dp = (const float*)d_in[1];
  const float* g  = (const float*)d_in[2];
  const int* pct  = (const int*)d_in[3];
  float* out = (float*)d_out;
  int E = in_sizes[0];

  uint8_t* ws = (uint8_t*)d_ws;
  const size_t STATE_OFF = 0;                        // 1 KiB
  const size_t HIST_OFF  = 4096;                     // 32 KiB
  const size_t EH1_OFF   = 65536;                    // 256 KiB
  const size_t EH2_OFF   = 327680;                   // 256 KiB
  const size_t MINI_OFF  = 589824;                   // 16 KiB
  const size_t LIST_OFF  = (size_t)1 << 20;          // 8 MiB (overlaps BH)
  const size_t ELIST_OFF = (size_t)9 << 20;          // 8 MiB (overlaps BH)
  const size_t BH_OFF    = (size_t)1 << 20;          // 16 MiB, dead after K2
  const size_t KEYS_OFF  = (size_t)17 << 20;         // E * 4 B

  if (ws_size < BH_OFF + (size_t)NB * NBINS * 4) {
    // cannot run selection; fail loudly via passthrough
    hipMemcpyAsync(out, v, (size_t)E * 4, hipMemcpyDeviceToDevice, stream);
    return;
  }
  bool use_keys = ws_size >= KEYS_OFF + (size_t)E * 4;

  unsigned* state  = (unsigned*)(ws + STATE_OFF);
  unsigned* hist   = (unsigned*)(ws + HIST_OFF);
  unsigned* ehist1 = (unsigned*)(ws + EH1_OFF);
  unsigned* ehist2 = (unsigned*)(ws + EH2_OFF);
  unsigned* mini   = (unsigned*)(ws + MINI_OFF);
  unsigned* list   = (unsigned*)(ws + LIST_OFF);
  unsigned* elist  = (unsigned*)(ws + ELIST_OFF);
  unsigned* bh     = (unsigned*)(ws + BH_OFF);
  unsigned* keys   = use_keys ? (unsigned*)(ws + KEYS_OFF) : nullptr;
  float delta = use_keys ? DELTA : 0.0f;

  // zero state + hist + ehist1 + ehist2 + mini (all below 1 MiB)
  hipMemsetAsync(ws, 0, (size_t)1 << 20, stream);

  key_hist1_kernel<<<NB, 512, 0, stream>>>(v, dp, g, keys, bh, E);
  reduce_hist_kernel<<<256, 256, 0, stream>>>(bh, hist);
  find_sel_kernel<<<1, 1024, 0, stream>>>(hist, state, pct, (long long)E, delta);
  output_kernel<<<1024, 512, 0, stream>>>(v, dp, g, keys, out, state, list, E);
  exact_eval_kernel<<<512, 256, 0, stream>>>(v, dp, g, list, elist, state, ehist1);
  find_e_kernel<<<1, 1024, 0, stream>>>(ehist1, state, 0);
  scatter2_kernel<<<256, 256, 0, stream>>>(elist, state, ehist2);
  find_e_kernel<<<1, 1024, 0, stream>>>(ehist2, state, 1);
  band_drop_kernel<<<256, 256, 0, stream>>>(list, elist, state, out, mini);
  mini_ties_kernel<<<1, 1024, 0, stream>>>(mini, state, out);
}

// Round 5
// 154.987 us; speedup vs baseline: 2.2650x; 2.2650x over previous
//
#include <hip/hip_runtime.h>
#include <hip/hip_bf16.h>
#include <stdint.h>

// ============================================================================
// AdaptiveEdgeDropping: out = matrix with top-k (k = E*pct/100) of
// (log_sigmoid(dp*(1-v) - g*v) + gumbel(key=42)) zeroed.  BIT-EXACT.
//
// Round 5: R4 pipeline, but the within-band exact select is rebuilt without
// global atomics (R4's exact_eval did ~500K device-scope atomicAdds onto ~8
// addresses -> 180us serialization). Now: offset-code d = ec - blo spans
// <~2^19; LDS block-hist of d>>SH (4096 bins) + coalesced no-atomic reduce +
// suffix select + tiled all-pairs rank of the ~300-member final bin.
// ============================================================================

#define NBINS 8192
#define NBINS_SHIFT 19            // approx code >> 19 -> 13-bit bin
#define NB 512                    // K1 histogram blocks
#define NB2 256                   // K5 histogram blocks
#define LIST_CAP 1572864u
#define MINI_CAP 16384u
#define DELTA 1e-3f
#define LBUF_CAP 2048
#define TIES_TILE 4096

// ---------------- threefry2x32, key=(0,42), counts=(0,i), out = x0^x1 -------
__device__ __forceinline__ unsigned tf_bits(unsigned i) {
  const unsigned ks0 = 0u;
  const unsigned ks1 = 42u;
  const unsigned ks2 = 0x1BD11BDAu ^ 0u ^ 42u;
  unsigned x0 = 0u + ks0;
  unsigned x1 = i + ks1;
#define TF_R(rot) { x0 += x1; x1 = (x1 << (rot)) | (x1 >> (32 - (rot))); x1 ^= x0; }
  TF_R(13) TF_R(15) TF_R(26) TF_R(6)
  x0 += ks1; x1 += ks2 + 1u;
  TF_R(17) TF_R(29) TF_R(16) TF_R(24)
  x0 += ks2; x1 += ks0 + 2u;
  TF_R(13) TF_R(15) TF_R(26) TF_R(6)
  x0 += ks0; x1 += ks1 + 3u;
  TF_R(17) TF_R(29) TF_R(16) TF_R(24)
  x0 += ks1; x1 += ks2 + 4u;
  TF_R(13) TF_R(15) TF_R(26) TF_R(6)
  x0 += ks2; x1 += ks0 + 5u;
#undef TF_R
  return x0 ^ x1;
}

// ---------------- jax.random.uniform(minval=1e-7, maxval=1-1e-7) -----------
__device__ __forceinline__ float uniform_from_bits(unsigned bits) {
  unsigned fb = (bits >> 9) | 0x3f800000u;
  float f = __uint_as_float(fb) - 1.0f;
  const float minv = 1e-7f;
  const float maxv = __uint_as_float(0x3F7FFFFEu);   // f32(1.0 - 1e-7)
  float r = __fsub_rn(maxv, minv);
  float u = __fadd_rn(__fmul_rn(f, r), minv);
  return fmaxf(minv, u);
}

// ---------------- XLA-CPU Cephes expf (unfused) ----------------------------
__device__ __forceinline__ float xla_expf(float input) {
  const float exp_hi = 88.3762626647950f;
  const float exp_lo = -88.3762626647949f;
  float x = fminf(fmaxf(input, exp_lo), exp_hi);
  float fx = floorf(__fadd_rn(__fmul_rn(x, 1.44269504088896341f), 0.5f));
  float tmp = __fmul_rn(0.693359375f, fx);
  float z = __fmul_rn(-2.12194440e-4f, fx);
  x = __fsub_rn(x, tmp);
  x = __fsub_rn(x, z);
  z = __fmul_rn(x, x);
  float y = __fadd_rn(__fmul_rn(x, 1.9875691500e-4f), 1.3981999507e-3f);
  y = __fadd_rn(__fmul_rn(y, x), 8.3334519073e-3f);
  y = __fadd_rn(__fmul_rn(y, x), 4.1665795894e-2f);
  y = __fadd_rn(__fmul_rn(y, x), 1.6666665459e-1f);
  y = __fadd_rn(__fmul_rn(y, x), 5.0000001201e-1f);
  y = __fadd_rn(__fmul_rn(y, z), x);
  y = __fadd_rn(1.0f, y);
  int n = (int)fx;
  float p2n = __int_as_float((n + 0x7f) << 23);
  return fmaxf(__fmul_rn(y, p2n), input);
}

// ---------------- XLA-CPU Cephes logf (Estrin, unfused) --------------------
__device__ __forceinline__ float xla_logf(float input) {
  float t0 = fmaxf(input, __uint_as_float(0x00800000u));
  unsigned ib = __float_as_uint(t0);
  int emm0 = (int)(ib >> 23) - 0x7f;
  float e = __fadd_rn(1.0f, (float)emm0);
  float m = __uint_as_float((ib & 0x807fffffu) | 0x3f000000u);
  bool mask = m < 0.707106781186547524f;
  float t1 = mask ? m : 0.0f;
  m = __fsub_rn(m, 1.0f);
  e = __fsub_rn(e, mask ? 1.0f : 0.0f);
  m = __fadd_rn(m, t1);
  float x2 = __fmul_rn(m, m);
  float x3 = __fmul_rn(x2, m);
  float y  = __fadd_rn(__fmul_rn(m, 7.0376836292e-2f), -1.1514610310e-1f);
  float y1 = __fadd_rn(__fmul_rn(m, -1.2420140846e-1f), 1.4249322787e-1f);
  float y2 = __fadd_rn(__fmul_rn(m, 2.0000714765e-1f), -2.4999993993e-1f);
  y  = __fadd_rn(__fmul_rn(y, m), 1.1676998740e-1f);
  y1 = __fadd_rn(__fmul_rn(y1, m), -1.6668057665e-1f);
  y2 = __fadd_rn(__fmul_rn(y2, m), 3.3333331174e-1f);
  y = __fadd_rn(__fmul_rn(y, x3), y1);
  y = __fadd_rn(__fmul_rn(y, x3), y2);
  y = __fmul_rn(y, x3);
  y = __fadd_rn(y, __fmul_rn(-2.12194440e-4f, e));
  y = __fsub_rn(y, __fmul_rn(0.5f, x2));
  m = __fadd_rn(m, y);
  m = __fadd_rn(m, __fmul_rn(0.693359375f, e));
  return m;
}

// ---------------- XLA elemental log1p --------------------------------------
__device__ __forceinline__ float xla_log1pf(float x) {
  float for_large = xla_logf(__fadd_rn(x, 1.0f));
  float for_small = __fmul_rn(__fadd_rn(__fmul_rn(-0.5f, x), 1.0f), x);
  return (fabsf(x) < 1e-4f) ? for_small : for_large;
}

// ---------------- monotone code <-> float ----------------------------------
__device__ __forceinline__ unsigned encode_f(float f) {
  unsigned b = __float_as_uint(f);
  return (b & 0x80000000u) ? ~b : (b | 0x80000000u);
}
__device__ __forceinline__ float decode_f(unsigned c) {
  unsigned b = (c & 0x80000000u) ? (c ^ 0x80000000u) : ~c;
  return __uint_as_float(b);
}

// ---------------- EXACT per-element key code (verified bit-exact) ----------
__device__ __forceinline__ unsigned compute_ou(unsigned i, float v, float dp, float g) {
  if (v == 0.0f) return 0u;
  unsigned bits = tf_bits(i);
  float u = uniform_from_bits(bits);
  float lg = xla_logf(u);
  float gum = -xla_logf(-lg);
  float t = __fsub_rn(1.0f, v);
  float lx = __fsub_rn(__fmul_rn(dp, t), __fmul_rn(g, v));
  float ex = xla_expf(-fabsf(lx));
  float l1p = xla_log1pf(ex);
  float lp = -(__fadd_rn(fmaxf(-lx, 0.0f), l1p));
  float key = __fadd_rn(lp, gum);
  return encode_f(key);
}

// ---------------- APPROX key code (HW transcendentals, |err| <= ~1e-6) -----
__device__ __forceinline__ unsigned approx_code(unsigned i, float v, float dp, float g) {
  if (v == 0.0f) return 0u;
  unsigned bits = tf_bits(i);
  float u = uniform_from_bits(bits);
  float lg = __logf(u);
  float gum = -__logf(-lg);
  float t = __fsub_rn(1.0f, v);
  float lx = __fsub_rn(__fmul_rn(dp, t), __fmul_rn(g, v));
  float ex = __expf(-fabsf(lx));
  float for_small = __fmul_rn(__fadd_rn(__fmul_rn(-0.5f, ex), 1.0f), ex);
  float l1p = (fabsf(ex) < 1e-4f) ? for_small : __logf(__fadd_rn(ex, 1.0f));
  float lp = -(__fadd_rn(fmaxf(-lx, 0.0f), l1p));
  float key = __fadd_rn(lp, gum);
  return encode_f(key);
}

// ============================================================================
// K1: keys (approx if stored, exact fallback), LDS 8192-bin hist, row flush.
// ============================================================================
__global__ __launch_bounds__(512) void key_hist1_kernel(
    const float* __restrict__ v, const float* __restrict__ dpp,
    const float* __restrict__ gp, unsigned* __restrict__ keys,
    unsigned* __restrict__ blockhist, int E) {
  __shared__ unsigned h[NBINS];
  for (int j = threadIdx.x; j < NBINS; j += 512) h[j] = 0;
  __syncthreads();
  float dp = dpp[0], g = gp[0];
  int nvec = E >> 2;
  int stride = gridDim.x * 512;
  for (int iv = blockIdx.x * 512 + threadIdx.x; iv < nvec; iv += stride) {
    float4 vv = reinterpret_cast<const float4*>(v)[iv];
    unsigned base = (unsigned)iv << 2;
    unsigned o0, o1, o2, o3;
    if (keys) {
      o0 = approx_code(base + 0u, vv.x, dp, g);
      o1 = approx_code(base + 1u, vv.y, dp, g);
      o2 = approx_code(base + 2u, vv.z, dp, g);
      o3 = approx_code(base + 3u, vv.w, dp, g);
      reinterpret_cast<uint4*>(keys)[iv] = make_uint4(o0, o1, o2, o3);
    } else {
      o0 = compute_ou(base + 0u, vv.x, dp, g);
      o1 = compute_ou(base + 1u, vv.y, dp, g);
      o2 = compute_ou(base + 2u, vv.z, dp, g);
      o3 = compute_ou(base + 3u, vv.w, dp, g);
    }
    atomicAdd(&h[o0 >> NBINS_SHIFT], 1u);
    atomicAdd(&h[o1 >> NBINS_SHIFT], 1u);
    atomicAdd(&h[o2 >> NBINS_SHIFT], 1u);
    atomicAdd(&h[o3 >> NBINS_SHIFT], 1u);
  }
  if (blockIdx.x == 0) {                       // tail (E % 4)
    for (int i = (nvec << 2) + threadIdx.x; i < E; i += 512) {
      float val = v[i];
      unsigned ou = keys ? approx_code((unsigned)i, val, dp, g)
                         : compute_ou((unsigned)i, val, dp, g);
      if (keys) keys[i] = ou;
      atomicAdd(&h[ou >> NBINS_SHIFT], 1u);
    }
  }
  __syncthreads();
  unsigned* row = blockhist + (size_t)blockIdx.x * NBINS;
  for (int j = threadIdx.x; j < NBINS; j += 512) row[j] = h[j];
}

// ============================================================================
// K2: hist[j] += sum_b blockhist[b][j]   (hist pre-zeroed; 8 slices)
// ============================================================================
#define RED_SLICES 8
__global__ __launch_bounds__(256) void reduce_hist_kernel(
    const unsigned* __restrict__ blockhist, unsigned* __restrict__ hist) {
  int gid = blockIdx.x * 256 + threadIdx.x;   // 256 blocks -> 65536 threads
  int j = gid & (NBINS - 1);
  int slice = gid >> 13;                      // 0..7
  unsigned s = 0;
  for (int b = slice; b < NB; b += RED_SLICES)
    s += blockhist[(size_t)b * NBINS + j];
  atomicAdd(&hist[j], s);
}

// ============================================================================
// K3: select over 8192 bins -> band [blo, bhi] +-delta; offset shift SH.
// state[0]=B, [2]=blo, [3]=bhi, [6]=k, [12]=SH.
// ============================================================================
__global__ __launch_bounds__(1024) void find_sel_kernel(
    const unsigned* __restrict__ hist, unsigned* __restrict__ state,
    const int* __restrict__ pct_p, long long Etot, float delta) {
  __shared__ unsigned s[1024];
  int t = threadIdx.x;
  unsigned hh[8];
  unsigned tot = 0;
  #pragma unroll
  for (int j = 0; j < 8; ++j) { hh[j] = hist[t * 8 + j]; tot += hh[j]; }
  s[t] = tot;
  __syncthreads();
  for (int off = 1; off < 1024; off <<= 1) {
    unsigned add = (t + off < 1024) ? s[t + off] : 0u;
    __syncthreads();
    s[t] += add;
    __syncthreads();
  }
  long long k = (Etot * (long long)pct_p[0]) / 100;
  long long above_next = (t < 1023) ? (long long)s[t + 1] : 0;
  if (above_next < k && k <= above_next + (long long)tot) {
    long long above = above_next;
    int b = 7;
    for (; b >= 0; --b) {
      if (above < k && k <= above + (long long)hh[b]) break;
      above += (long long)hh[b];
    }
    unsigned B = (unsigned)(t * 8 + b);
    state[0] = B;
    state[6] = (unsigned)k;
    float L = decode_f(B << NBINS_SHIFT);
    unsigned blo = encode_f(L - delta);
    unsigned bhi;
    if (B == NBINS - 1u) bhi = 0xFFFFFFFFu;
    else {
      float H = decode_f((B + 1u) << NBINS_SHIFT);
      bhi = encode_f(H + delta);
    }
    state[2] = blo;
    state[3] = bhi;
    unsigned span = bhi - blo;
    unsigned sh = 0;
    while ((span >> sh) >= 4096u) ++sh;
    state[12] = sh;
  }
}

// ============================================================================
// K4: streaming output (code > bhi -> 0); band indices -> LDS-compacted list;
// |A| counted via shfl + one global atomic per block. No exact eval here.
// ============================================================================
__global__ __launch_bounds__(512) void output_kernel(
    const float* __restrict__ v, const float* __restrict__ dpp,
    const float* __restrict__ gp, const unsigned* __restrict__ keys,
    float* __restrict__ out, unsigned* __restrict__ state,
    unsigned* __restrict__ list, int E) {
  __shared__ unsigned lcnt, lbase, sacc;
  __shared__ unsigned lbuf[LBUF_CAP];
  if (threadIdx.x == 0) { lcnt = 0; sacc = 0; }
  __syncthreads();
  unsigned blo = state[2], bhi = state[3];
  float dp = dpp[0], g = gp[0];
  int nvec = E >> 2;
  int stride = gridDim.x * 512;
  unsigned acnt = 0;
  for (int iv = blockIdx.x * 512 + threadIdx.x; iv < nvec; iv += stride) {
    float4 vv = reinterpret_cast<const float4*>(v)[iv];
    unsigned base = (unsigned)iv << 2;
    unsigned os[4];
    if (keys) {
      uint4 kk = reinterpret_cast<const uint4*>(keys)[iv];
      os[0] = kk.x; os[1] = kk.y; os[2] = kk.z; os[3] = kk.w;
    } else {
      os[0] = compute_ou(base + 0u, vv.x, dp, g);
      os[1] = compute_ou(base + 1u, vv.y, dp, g);
      os[2] = compute_ou(base + 2u, vv.z, dp, g);
      os[3] = compute_ou(base + 3u, vv.w, dp, g);
    }
    float vals[4] = {vv.x, vv.y, vv.z, vv.w};
    float4 oo;
    float res[4];
    #pragma unroll
    for (int j = 0; j < 4; ++j) {
      bool drop = os[j] > bhi;
      acnt += drop ? 1u : 0u;
      res[j] = drop ? 0.0f : vals[j];
      if (!drop && os[j] >= blo) {
        unsigned p = atomicAdd(&lcnt, 1u);
        if (p < LBUF_CAP) lbuf[p] = base + (unsigned)j;
        else {
          unsigned q = atomicAdd(&state[4], 1u);
          if (q < LIST_CAP) list[q] = base + (unsigned)j;
        }
      }
    }
    oo.x = res[0]; oo.y = res[1]; oo.z = res[2]; oo.w = res[3];
    reinterpret_cast<float4*>(out)[iv] = oo;
  }
  if (blockIdx.x == 0) {
    for (int i = (nvec << 2) + threadIdx.x; i < E; i += 512) {
      float val = v[i];
      unsigned ou = keys ? keys[i] : compute_ou((unsigned)i, val, dp, g);
      bool drop = ou > bhi;
      acnt += drop ? 1u : 0u;
      out[i] = drop ? 0.0f : val;
      if (!drop && ou >= blo) {
        unsigned p = atomicAdd(&lcnt, 1u);
        if (p < LBUF_CAP) lbuf[p] = (unsigned)i;
        else {
          unsigned q = atomicAdd(&state[4], 1u);
          if (q < LIST_CAP) list[q] = (unsigned)i;
        }
      }
    }
  }
  #pragma unroll
  for (int off = 32; off > 0; off >>= 1) acnt += __shfl_xor(acnt, off);
  if ((threadIdx.x & 63) == 0 && acnt) atomicAdd(&sacc, acnt);
  __syncthreads();
  if (threadIdx.x == 0) {
    unsigned n = min(lcnt, (unsigned)LBUF_CAP);
    lbase = atomicAdd(&state[4], n);
    if (sacc) atomicAdd(&state[5], sacc);
  }
  __syncthreads();
  unsigned n = min(lcnt, (unsigned)LBUF_CAP);
  for (unsigned j = threadIdx.x; j < n; j += 512) {
    unsigned q = lbase + j;
    if (q < LIST_CAP) list[q] = lbuf[j];
  }
}

// ---------------- offset-code bin (clamped) --------------------------------
__device__ __forceinline__ unsigned band_bin(unsigned ec, unsigned blo,
                                             unsigned span, unsigned sh) {
  if (ec <= blo) return 0u;
  unsigned d = ec - blo;
  if (d > span) d = span;
  return d >> sh;                       // < 4096 by construction of sh
}

// ============================================================================
// K5: dense exact eval over band list -> elist; LDS 4096-bin hist of
// (ec - blo) >> SH; per-block row flush (NO global atomics).
// ============================================================================
__global__ __launch_bounds__(256) void exact_eval_kernel(
    const float* __restrict__ v, const float* __restrict__ dpp,
    const float* __restrict__ gp, const unsigned* __restrict__ list,
    unsigned* __restrict__ elist, const unsigned* __restrict__ state,
    unsigned* __restrict__ blockhist2) {
  __shared__ unsigned h[4096];
  for (int j = threadIdx.x; j < 4096; j += 256) h[j] = 0;
  __syncthreads();
  unsigned M = min(state[4], LIST_CAP);
  unsigned blo = state[2], span = state[3] - state[2], sh = state[12];
  float dp = dpp[0], g = gp[0];
  for (unsigned e = blockIdx.x * 256 + threadIdx.x; e < M; e += gridDim.x * 256) {
    unsigned idx = list[e];
    unsigned ec = compute_ou(idx, v[idx], dp, g);
    elist[e] = ec;
    atomicAdd(&h[band_bin(ec, blo, span, sh)], 1u);
  }
  __syncthreads();
  unsigned* row = blockhist2 + (size_t)blockIdx.x * 4096;
  for (int j = threadIdx.x; j < 4096; j += 256) row[j] = h[j];
}

// ============================================================================
// K6: hist2[j] = sum_b blockhist2[b][j]  (coalesced columns, no atomics)
// ============================================================================
__global__ __launch_bounds__(256) void reduce_hist2_kernel(
    const unsigned* __restrict__ blockhist2, unsigned* __restrict__ hist2) {
  int j = blockIdx.x * 256 + threadIdx.x;     // 16 blocks -> 4096 threads
  unsigned s = 0;
  for (int b = 0; b < NB2; ++b) s += blockhist2[(size_t)b * 4096 + j];
  hist2[j] = s;
}

// ============================================================================
// K7: suffix select over 4096 offset bins. kp = k - |A|.
// state[7]=Eb (bin), state[8]=r (drop count within Eb).
// ============================================================================
__global__ __launch_bounds__(1024) void find_band_kernel(
    const unsigned* __restrict__ hist2, unsigned* __restrict__ state) {
  __shared__ unsigned s[1024];
  int t = threadIdx.x;
  unsigned hh[4];
  unsigned tot = 0;
  #pragma unroll
  for (int j = 0; j < 4; ++j) { hh[j] = hist2[t * 4 + j]; tot += hh[j]; }
  s[t] = tot;
  __syncthreads();
  for (int off = 1; off < 1024; off <<= 1) {
    unsigned add = (t + off < 1024) ? s[t + off] : 0u;
    __syncthreads();
    s[t] += add;
    __syncthreads();
  }
  unsigned kp = state[6] - state[5];          // k - |A|
  if (kp == 0u || kp > s[0]) {
    if (t == 0) { state[7] = 0xFFFFFFFFu; state[8] = 0u; }
    return;
  }
  unsigned above_next = (t < 1023) ? s[t + 1] : 0u;
  if (above_next < kp && kp <= s[t]) {
    unsigned above = above_next;
    for (int b = 3; b >= 0; --b) {
      if (above < kp && kp <= above + hh[b]) {
        state[7] = (unsigned)(t * 4 + b);
        state[8] = kp - above;
        break;
      }
      above += hh[b];
    }
  }
}

// ============================================================================
// K8: drop band members with bin > Eb; bin == Eb -> mini (ec, idx).
// ============================================================================
__global__ __launch_bounds__(256) void band_drop_kernel(
    const unsigned* __restrict__ list, const unsigned* __restrict__ elist,
    unsigned* __restrict__ state, float* __restrict__ out,
    uint2* __restrict__ mini) {
  unsigned M = min(state[4], LIST_CAP);
  unsigned Eb = state[7];
  unsigned blo = state[2], span = state[3] - state[2], sh = state[12];
  for (unsigned e = blockIdx.x * 256 + threadIdx.x; e < M; e += gridDim.x * 256) {
    unsigned ec = elist[e];
    unsigned bin = band_bin(ec, blo, span, sh);
    if (bin > Eb) out[list[e]] = 0.0f;
    else if (bin == Eb) {
      unsigned q = atomicAdd(&state[11], 1u);
      if (q < MINI_CAP) mini[q] = make_uint2(ec, list[e]);
    }
  }
}

// ============================================================================
// K9: tiled all-pairs rank among mini by (ec desc, idx asc); drop top r.
// ============================================================================
__global__ __launch_bounds__(1024) void mini_ties_kernel(
    const uint2* __restrict__ mini, const unsigned* __restrict__ state,
    float* __restrict__ out) {
  __shared__ uint2 tile[TIES_TILE];
  unsigned m = min(state[11], MINI_CAP);
  unsigned r = state[8];
  if (r == 0u || m == 0u) return;
  int tid = threadIdx.x;
  for (unsigned e0 = 0; e0 < m; e0 += blockDim.x) {
    unsigned e = e0 + tid;
    bool valid = e < m;
    unsigned my_ec = 0, my_idx = 0;
    if (valid) { uint2 me = mini[e]; my_ec = me.x; my_idx = me.y; }
    unsigned rank = 0;
    for (unsigned t0 = 0; t0 < m; t0 += TIES_TILE) {
      unsigned tn = min((unsigned)TIES_TILE, m - t0);
      __syncthreads();
      for (unsigned j = tid; j < tn; j += blockDim.x) tile[j] = mini[t0 + j];
      __syncthreads();
      if (valid) {
        for (unsigned j = 0; j < tn; ++j) {
          uint2 o = tile[j];
          rank += (o.x > my_ec || (o.x == my_ec && o.y < my_idx)) ? 1u : 0u;
        }
      }
    }
    if (valid && rank < r) out[my_idx] = 0.0f;
  }
}

// ---------------- launch ----------------------------------------------------
extern "C" void kernel_launch(void* const* d_in, const int* in_sizes, int n_in,
                              void* d_out, int out_size, void* d_ws, size_t ws_size,
                              hipStream_t stream) {
  const float* v  = (const float*)d_in[0];
  const float* dp = (const float*)d_in[1];
  const float* g  = (const float*)d_in[2];
  const int* pct  = (const int*)d_in[3];
  float* out = (float*)d_out;
  int E = in_sizes[0];

  uint8_t* ws = (uint8_t*)d_ws;
  // 84 MiB total footprint (same as R4, which fit):
  //   [0, 1MiB):   state(1KiB) | hist(32KiB@4KiB) | hist2(16KiB@40KiB) |
  //                mini(128KiB@64KiB)
  //   [1, 17MiB):  BH (512x8192x4 = 16MiB)  -- dead after K2, then reused:
  //                  BH2 (256x4096x4 = 4MiB) @ 1MiB
  //                  list (1.5Mx4 = 6MiB)   @ 5MiB
  //                  elist (1.5Mx4 = 6MiB)  @ 11MiB
  //   [17MiB, +E*4): keys
  const size_t STATE_OFF = 0;
  const size_t HIST_OFF  = 4096;
  const size_t HIST2_OFF = 40 * 1024;
  const size_t MINI_OFF  = 64 * 1024;
  const size_t BH_OFF    = (size_t)1 << 20;
  const size_t BH2_OFF   = (size_t)1 << 20;
  const size_t LIST_OFF  = (size_t)5 << 20;
  const size_t ELIST_OFF = (size_t)11 << 20;
  const size_t KEYS_OFF  = (size_t)17 << 20;

  if (ws_size < BH_OFF + (size_t)NB * NBINS * 4) {
    // cannot run selection; fail loudly via passthrough
    hipMemcpyAsync(out, v, (size_t)E * 4, hipMemcpyDeviceToDevice, stream);
    return;
  }
  bool use_keys = ws_size >= KEYS_OFF + (size_t)E * 4;

  unsigned* state  = (unsigned*)(ws + STATE_OFF);
  unsigned* hist   = (unsigned*)(ws + HIST_OFF);
  unsigned* hist2  = (unsigned*)(ws + HIST2_OFF);
  uint2*    mini   = (uint2*)(ws + MINI_OFF);
  unsigned* bh     = (unsigned*)(ws + BH_OFF);
  unsigned* bh2    = (unsigned*)(ws + BH2_OFF);
  unsigned* list   = (unsigned*)(ws + LIST_OFF);
  unsigned* elist  = (unsigned*)(ws + ELIST_OFF);
  unsigned* keys   = use_keys ? (unsigned*)(ws + KEYS_OFF) : nullptr;
  float delta = use_keys ? DELTA : 0.0f;

  // zero state + hist + hist2 (+mini area, harmless): first 1 MiB
  hipMemsetAsync(ws, 0, (size_t)1 << 20, stream);

  key_hist1_kernel<<<NB, 512, 0, stream>>>(v, dp, g, keys, bh, E);
  reduce_hist_kernel<<<256, 256, 0, stream>>>(bh, hist);
  find_sel_kernel<<<1, 1024, 0, stream>>>(hist, state, pct, (long long)E, delta);
  output_kernel<<<1024, 512, 0, stream>>>(v, dp, g, keys, out, state, list, E);
  exact_eval_kernel<<<NB2, 256, 0, stream>>>(v, dp, g, list, elist, state, bh2);
  reduce_hist2_kernel<<<16, 256, 0, stream>>>(bh2, hist2);
  find_band_kernel<<<1, 1024, 0, stream>>>(hist2, state);
  band_drop_kernel<<<256, 256, 0, stream>>>(list, elist, state, out, mini);
  mini_ties_kernel<<<1, 1024, 0, stream>>>(mini, state, out);
}